// Round 1
// baseline (421.210 us; speedup 1.0000x reference)
//
#include <hip/hip_runtime.h>
#include <hip/hip_bf16.h>
#include <math.h>

#define CIN  64
#define COUT 32
#define K1V  17
#define HV   4

// Kernel A: xp[m, o] = sum_i x[m, i] * W[o, i] + b[o]
// One thread per (row m, out-channel o). Lanes 0..31 share row m0, lanes
// 32..63 share row m1 -> x loads are 2-address broadcasts; W (8KB) lives in L1.
__global__ __launch_bounds__(256) void proj_kernel(
    const float* __restrict__ x, const float* __restrict__ W,
    const float* __restrict__ b, float* __restrict__ xp, long total) {
  long gid = (long)blockIdx.x * blockDim.x + threadIdx.x;
  if (gid >= total) return;
  long m = gid >> 5;
  int  o = (int)(gid & 31);
  const float4* xr = (const float4*)(x + m * CIN);
  const float4* wr = (const float4*)(W + (long)o * CIN);
  float acc = b[o];
#pragma unroll
  for (int j = 0; j < CIN / 4; ++j) {
    float4 xv = xr[j];
    float4 wv = wr[j];
    acc += xv.x * wv.x + xv.y * wv.y + xv.z * wv.z + xv.w * wv.w;
  }
  xp[gid] = acc;  // contiguous -> coalesced
}

// Kernel C: out[bt, n, h, c] = sum_k w[n,k,h] * xp[bt, nn[n,k], c] + dist_agg[n,h]
// Block = 256 threads = 2 nodes x 4 heads x 32 channels.
__global__ __launch_bounds__(256) void gcn_kernel(
    const float* __restrict__ xp,    // (BT, N, 32)
    const float* __restrict__ dist,  // (N, K1)
    const int*   __restrict__ nn,    // (N, K1)
    float* __restrict__ out,         // (BT, N, H, 32)
    int BT, int N) {
  __shared__ float wl[2][K1V * HV];
  __shared__ float dl[2][K1V];
  __shared__ int   nl[2][K1V];

  int tid = threadIdx.x;
  int ln  = tid >> 7;         // local node 0/1
  int lh  = (tid >> 5) & 3;   // head
  int c   = tid & 31;         // channel

  int pairs = (N + 1) / 2;
  long bid = blockIdx.x;
  int bt = (int)(bid / pairs);
  int pr = (int)(bid % pairs);
  int n  = pr * 2 + ln;

  // Cooperative w-table: 2 * 17 * 4 = 136 entries
  if (tid < 2 * K1V * HV) {
    int l   = tid / (K1V * HV);
    int rem = tid % (K1V * HV);
    int k   = rem / HV;
    int h   = rem % HV;
    int n_  = pr * 2 + l;
    if (n_ < N) {
      float d   = dist[(long)n_ * K1V + k];
      int   idx = nn[(long)n_ * K1V + k];
      float lam = (float)(h + 1) * (1.0f / HV);
      float w   = expf(-(d * d) * lam);   // SIGMA = 1
      if (idx == -1)  w = 0.0f;
      if (w < 1e-5f)  w = 0.0f;
      wl[l][k * HV + h] = w;
      if (h == 0) {
        dl[l][k] = isinf(d) ? 0.0f : d;
        nl[l][k] = idx;
      }
    }
  }
  __syncthreads();

  if (n >= N) return;

  // dist_agg term (redundant across c lanes; 17 FMAs, cheap)
  float acc = 0.0f;
#pragma unroll
  for (int k = 0; k < K1V; ++k) acc += wl[ln][k * HV + lh] * dl[ln][k];

  const float* xpb = xp + (size_t)bt * N * COUT;
#pragma unroll
  for (int k = 0; k < K1V; ++k) {
    int   idx = nl[ln][k];
    float w   = wl[ln][k * HV + lh];
    float v   = (idx >= 0 && idx < N) ? xpb[(size_t)idx * COUT + c] : 0.0f;
    acc += w * v;
  }

  out[(((size_t)bt * N + n) * HV + lh) * COUT + c] = acc;
}

extern "C" void kernel_launch(void* const* d_in, const int* in_sizes, int n_in,
                              void* d_out, int out_size, void* d_ws, size_t ws_size,
                              hipStream_t stream) {
  const float* x    = (const float*)d_in[0];
  const float* W    = (const float*)d_in[1];
  const float* b    = (const float*)d_in[2];
  const float* dist = (const float*)d_in[3];
  const int*   nn   = (const int*)d_in[4];
  float* out = (float*)d_out;
  float* xp  = (float*)d_ws;   // (BT, N, 32) fp32 = 30.72 MB

  int  N  = in_sizes[4] / K1V;                 // 10000
  long M  = (long)in_sizes[0] / CIN;           // BT * N = 240000
  int  BT = (int)(M / N);                      // 24

  long total = M * COUT;
  proj_kernel<<<(int)((total + 255) / 256), 256, 0, stream>>>(x, W, b, xp, total);

  int pairs = (N + 1) / 2;
  long blocks = (long)BT * pairs;              // 120000
  gcn_kernel<<<(int)blocks, 256, 0, stream>>>(xp, dist, nn, out, BT, N);
}

// Round 2
// 322.803 us; speedup vs baseline: 1.3049x; 1.3049x over previous
//
#include <hip/hip_runtime.h>
#include <hip/hip_bf16.h>
#include <math.h>

#define CIN  64
#define COUT 32
#define K1V  17
#define HV   4

// Kernel A: xp[r, o] = sum_i x[r, i] * W[o, i] + b[o]
// One thread per ROW, 32 accumulators in registers. W/b addressed uniformly
// -> scalar loads (8KB, L1-hot). x read exactly once per row.
__global__ __launch_bounds__(256) void proj_kernel(
    const float* __restrict__ x, const float* __restrict__ W,
    const float* __restrict__ b, float* __restrict__ xp, long nrows) {
  long r = (long)blockIdx.x * blockDim.x + threadIdx.x;
  if (r >= nrows) return;
  const float4* xr = (const float4*)(x + r * CIN);
  float acc[COUT];
#pragma unroll
  for (int o = 0; o < COUT; ++o) acc[o] = b[o];
#pragma unroll
  for (int j = 0; j < CIN / 4; ++j) {
    float4 xv = xr[j];
#pragma unroll
    for (int o = 0; o < COUT; ++o) {
      float4 wv = *(const float4*)(W + o * CIN + j * 4);  // uniform addr
      acc[o] += xv.x * wv.x + xv.y * wv.y + xv.z * wv.z + xv.w * wv.w;
    }
  }
  float4* op = (float4*)(xp + r * COUT);
#pragma unroll
  for (int j = 0; j < COUT / 4; ++j)
    op[j] = make_float4(acc[4 * j], acc[4 * j + 1], acc[4 * j + 2], acc[4 * j + 3]);
}

// Kernel C: block = 2 nodes x 4 heads x 32 ch; ONE block handles its node
// pair for ALL BT time-batch slices (w-table built once, hoisted to regs).
__global__ __launch_bounds__(256) void gcn_kernel(
    const float* __restrict__ xp,    // (BT, N, 32)
    const float* __restrict__ dist,  // (N, K1)
    const int*   __restrict__ nn,    // (N, K1)
    float* __restrict__ out,         // (BT, N, H, 32)
    int BT, int N) {
  __shared__ float wl[2][K1V * HV];
  __shared__ float dl[2][K1V];
  __shared__ int   nl[2][K1V];

  int tid = threadIdx.x;
  int ln  = tid >> 7;         // local node 0/1
  int lh  = (tid >> 5) & 3;   // head
  int c   = tid & 31;         // channel
  int pr  = blockIdx.x;
  int n   = pr * 2 + ln;

  // Cooperative w-table: 2 * 17 * 4 = 136 entries
  if (tid < 2 * K1V * HV) {
    int l   = tid / (K1V * HV);
    int rem = tid % (K1V * HV);
    int k   = rem / HV;
    int h   = rem % HV;
    int n_  = pr * 2 + l;
    if (n_ < N) {
      float d   = dist[(long)n_ * K1V + k];
      int   idx = nn[(long)n_ * K1V + k];
      float lam = (float)(h + 1) * (1.0f / HV);
      float w   = expf(-(d * d) * lam);   // SIGMA = 1
      if (idx == -1)  w = 0.0f;
      if (w < 1e-5f)  w = 0.0f;
      wl[l][k * HV + h] = w;
      if (h == 0) {
        dl[l][k] = isinf(d) ? 0.0f : d;
        nl[l][k] = idx;
      }
    }
  }
  __syncthreads();

  if (n >= N) return;

  // Hoist weights + gather offsets into registers; precompute dist_agg.
  float wreg[K1V];
  int   off[K1V];
  float dag = 0.0f;
#pragma unroll
  for (int k = 0; k < K1V; ++k) {
    wreg[k] = wl[ln][k * HV + lh];
    dag    += wreg[k] * dl[ln][k];
    int idx = nl[ln][k];
    // invalid idx has wreg==0; point it at a safe in-bounds address
    off[k]  = (idx >= 0 && idx < N) ? idx * COUT + c : c;
  }

  size_t outbase = ((size_t)n * HV + lh) * COUT + c;
  size_t btO     = (size_t)N * HV * COUT;
  const float* xpb = xp;
  for (int bt = 0; bt < BT; ++bt) {
    float acc = dag;
#pragma unroll
    for (int k = 0; k < K1V; ++k) acc += wreg[k] * xpb[off[k]];
    out[outbase + (size_t)bt * btO] = acc;
    xpb += (size_t)N * COUT;
  }
}

extern "C" void kernel_launch(void* const* d_in, const int* in_sizes, int n_in,
                              void* d_out, int out_size, void* d_ws, size_t ws_size,
                              hipStream_t stream) {
  const float* x    = (const float*)d_in[0];
  const float* W    = (const float*)d_in[1];
  const float* b    = (const float*)d_in[2];
  const float* dist = (const float*)d_in[3];
  const int*   nn   = (const int*)d_in[4];
  float* out = (float*)d_out;
  float* xp  = (float*)d_ws;   // (BT, N, 32) fp32 = 30.72 MB

  int  N  = in_sizes[4] / K1V;                 // 10000
  long M  = (long)in_sizes[0] / CIN;           // BT * N = 240000
  int  BT = (int)(M / N);                      // 24

  proj_kernel<<<(int)((M + 255) / 256), 256, 0, stream>>>(x, W, b, xp, M);

  int pairs = (N + 1) / 2;                     // 5000 blocks
  gcn_kernel<<<pairs, 256, 0, stream>>>(xp, dist, nn, out, BT, N);
}

// Round 3
// 268.747 us; speedup vs baseline: 1.5673x; 1.2011x over previous
//
#include <hip/hip_runtime.h>
#include <hip/hip_bf16.h>
#include <math.h>

#define CIN  64
#define COUT 32
#define K1V  17
#define HV   4

// Kernel A: xp[r,o] = sum_i x[r,i]*W[o,i] + b[o]
// W+b staged in LDS (broadcast reads); full row in 16 float4 regs upfront
// (independent loads -> MLP); acc[32] in regs; float4 stores.
__global__ __launch_bounds__(256, 4) void proj_kernel(
    const float* __restrict__ x, const float* __restrict__ W,
    const float* __restrict__ b, float* __restrict__ xp, long nrows) {
  __shared__ float Wl[COUT * CIN];   // 8 KB
  __shared__ float bl[COUT];
  int tid = threadIdx.x;
  {
    const float4* Wg = (const float4*)W;
    float4* Ws = (float4*)Wl;
    Ws[tid]       = Wg[tid];         // 512 float4 total, 256 threads x2
    Ws[tid + 256] = Wg[tid + 256];
    if (tid < COUT) bl[tid] = b[tid];
  }
  __syncthreads();

  long r = (long)blockIdx.x * blockDim.x + tid;
  if (r >= nrows) return;

  const float4* xr = (const float4*)(x + r * CIN);
  float4 xv[CIN / 4];
#pragma unroll
  for (int j = 0; j < CIN / 4; ++j) xv[j] = xr[j];

  float acc[COUT];
#pragma unroll
  for (int o = 0; o < COUT; ++o) acc[o] = bl[o];

#pragma unroll
  for (int j = 0; j < CIN / 4; ++j) {
#pragma unroll
    for (int o = 0; o < COUT; ++o) {
      float4 wv = *(const float4*)&Wl[o * CIN + j * 4];  // uniform -> broadcast
      acc[o] += xv[j].x * wv.x + xv[j].y * wv.y + xv[j].z * wv.z + xv[j].w * wv.w;
    }
  }

  float4* op = (float4*)(xp + r * COUT);
#pragma unroll
  for (int q = 0; q < COUT / 4; ++q)
    op[q] = make_float4(acc[4*q], acc[4*q+1], acc[4*q+2], acc[4*q+3]);
}

// Kernel C: block = 4 nodes x 2 head-pairs x 32 ch = 256 threads.
// Each thread: 2 head accumulators; one gather load feeds 2 FMAs.
// dist_agg folded into accumulator init. Loops all BT (table amortized).
__global__ __launch_bounds__(256, 4) void gcn_kernel(
    const float* __restrict__ xp,    // (BT, N, 32)
    const float* __restrict__ dist,  // (N, K1)
    const int*   __restrict__ nn,    // (N, K1)
    float* __restrict__ out,         // (BT, N, H, 32)
    int BT, int N) {
  __shared__ float wl[4][K1V][HV];
  __shared__ float dl[4][K1V];
  __shared__ int   nl[4][K1V];

  int tid = threadIdx.x;
  int ln = tid >> 6;          // local node 0..3 (= wave id)
  int hp = (tid >> 5) & 1;    // head pair 0 (h0,h1) / 1 (h2,h3)
  int c  = tid & 31;          // channel
  int n0 = blockIdx.x * 4;

  if (tid < 4 * K1V) {        // 68 builder threads
    int l = tid / K1V, k = tid % K1V;
    int n_ = n0 + l;
    float w0 = 0, w1 = 0, w2 = 0, w3 = 0, dc = 0;
    int idx = 0;
    if (n_ < N) {
      float d = dist[(long)n_ * K1V + k];
      idx = nn[(long)n_ * K1V + k];
      float d2 = d * d;
      w0 = expf(-d2 * 0.25f);
      w1 = expf(-d2 * 0.50f);
      w2 = expf(-d2 * 0.75f);
      w3 = expf(-d2);
      if (idx == -1) { w0 = w1 = w2 = w3 = 0.0f; }
      if (w0 < 1e-5f) w0 = 0.0f;
      if (w1 < 1e-5f) w1 = 0.0f;
      if (w2 < 1e-5f) w2 = 0.0f;
      if (w3 < 1e-5f) w3 = 0.0f;
      dc = isinf(d) ? 0.0f : d;
      if (idx < 0 || idx >= N) idx = 0;   // w==0 there; safe addr
    }
    wl[l][k][0] = w0; wl[l][k][1] = w1; wl[l][k][2] = w2; wl[l][k][3] = w3;
    dl[l][k] = dc; nl[l][k] = idx;
  }
  __syncthreads();

  int n = n0 + ln;
  if (n >= N) return;

  // byte offsets in regs; dist_agg folded into init
  int off[K1V];
  float dag0 = 0.0f, dag1 = 0.0f;
#pragma unroll
  for (int k = 0; k < K1V; ++k) {
    off[k] = nl[ln][k] * (COUT * 4) + c * 4;
    float2 wv = *(const float2*)&wl[ln][k][2 * hp];
    float dc = dl[ln][k];
    dag0 += wv.x * dc;
    dag1 += wv.y * dc;
  }

  const char* xpb = (const char*)xp;
  size_t sliceB  = (size_t)N * COUT * 4;
  float* ob      = out + ((size_t)n * HV + 2 * hp) * COUT + c;
  size_t ostride = (size_t)N * HV * COUT;

  for (int bt = 0; bt < BT; ++bt) {
    float a0 = dag0, a1 = dag1;
#pragma unroll
    for (int k = 0; k < K1V; ++k) {
      float v = *(const float*)(xpb + off[k]);
      float2 wv = *(const float2*)&wl[ln][k][2 * hp];
      a0 += wv.x * v;
      a1 += wv.y * v;
    }
    ob[0]    = a0;
    ob[COUT] = a1;
    xpb += sliceB;
    ob  += ostride;
  }
}

extern "C" void kernel_launch(void* const* d_in, const int* in_sizes, int n_in,
                              void* d_out, int out_size, void* d_ws, size_t ws_size,
                              hipStream_t stream) {
  const float* x    = (const float*)d_in[0];
  const float* W    = (const float*)d_in[1];
  const float* b    = (const float*)d_in[2];
  const float* dist = (const float*)d_in[3];
  const int*   nn   = (const int*)d_in[4];
  float* out = (float*)d_out;
  float* xp  = (float*)d_ws;   // (BT, N, 32) fp32 = 30.72 MB

  int  N  = in_sizes[4] / K1V;                 // 10000
  long M  = (long)in_sizes[0] / CIN;           // BT * N = 240000
  int  BT = (int)(M / N);                      // 24

  proj_kernel<<<(int)((M + 255) / 256), 256, 0, stream>>>(x, W, b, xp, M);

  int nblocks = (N + 3) / 4;                   // 2500
  gcn_kernel<<<nblocks, 256, 0, stream>>>(xp, dist, nn, out, BT, N);
}

// Round 4
// 126.047 us; speedup vs baseline: 3.3417x; 2.1321x over previous
//
#include <hip/hip_runtime.h>
#include <hip/hip_bf16.h>
#include <math.h>

#define CIN   64
#define COUT  32
#define K1V   17
#define HV    4
#define BTILE 6

// Kernel A: xp[r,o] = sum_i x[r,i]*W[o,i] + b[o]
// One thread per row. All 16 row float4 loads issued upfront (independent,
// in flight together). W/b addresses are wave-uniform -> scalar s_loads
// through the constant cache (W is 8KB, stays hot). acc[32] in regs.
// __launch_bounds__(256,1): let the compiler keep ~110 VGPRs, NO spills.
__global__ __launch_bounds__(256, 1) void proj_kernel(
    const float* __restrict__ x, const float* __restrict__ W,
    const float* __restrict__ b, float* __restrict__ xp, long nrows) {
  long r = (long)blockIdx.x * blockDim.x + threadIdx.x;
  if (r >= nrows) return;

  const float4* xr = (const float4*)(x + r * CIN);
  float4 xv[CIN / 4];
#pragma unroll
  for (int j = 0; j < CIN / 4; ++j) xv[j] = xr[j];   // 16 loads in flight

  float acc[COUT];
#pragma unroll
  for (int o = 0; o < COUT; ++o) acc[o] = b[o];

#pragma unroll
  for (int j = 0; j < CIN / 4; ++j) {
#pragma unroll
    for (int o = 0; o < COUT; ++o) {
      float4 wv = *(const float4*)(W + o * CIN + j * 4);  // uniform -> s_load
      acc[o] = fmaf(xv[j].x, wv.x, acc[o]);
      acc[o] = fmaf(xv[j].y, wv.y, acc[o]);
      acc[o] = fmaf(xv[j].z, wv.z, acc[o]);
      acc[o] = fmaf(xv[j].w, wv.w, acc[o]);
    }
  }

  float4* op = (float4*)(xp + r * COUT);
#pragma unroll
  for (int q = 0; q < COUT / 4; ++q)
    op[q] = make_float4(acc[4*q], acc[4*q+1], acc[4*q+2], acc[4*q+3]);
}

// Kernel C: block = 8 nodes x 32 ch = 256 threads; each thread owns all 4
// heads of one (node, channel). bt tiled by 6: per k, ONE w-float4 LDS read
// feeds 6 independent gathers x 4 FMAs -> 6x fewer LDS reads, deep MLP.
// dist_agg folded into accumulator init. Streaming nt stores for out.
__global__ __launch_bounds__(256) void gcn_kernel(
    const float* __restrict__ xp,    // (BT, N, 32)
    const float* __restrict__ dist,  // (N, K1)
    const int*   __restrict__ nn,    // (N, K1)
    float* __restrict__ out,         // (BT, N, H, 32)
    int BT, int N) {
  __shared__ float wl[8][K1V][HV];
  __shared__ float dl[8][K1V];
  __shared__ int   nl[8][K1V];

  int tid = threadIdx.x;
  int ln  = tid >> 5;         // local node 0..7
  int c   = tid & 31;         // channel
  int n0  = blockIdx.x * 8;

  if (tid < 8 * K1V) {        // 136 builder threads
    int l = tid / K1V, k = tid % K1V;
    int n_ = n0 + l;
    float w0 = 0, w1 = 0, w2 = 0, w3 = 0, dc = 0;
    int idx = 0;
    if (n_ < N) {
      float d = dist[(long)n_ * K1V + k];
      idx = nn[(long)n_ * K1V + k];
      float d2 = d * d;
      w0 = expf(-d2 * 0.25f);
      w1 = expf(-d2 * 0.50f);
      w2 = expf(-d2 * 0.75f);
      w3 = expf(-d2);
      if (idx == -1) { w0 = w1 = w2 = w3 = 0.0f; }
      if (w0 < 1e-5f) w0 = 0.0f;
      if (w1 < 1e-5f) w1 = 0.0f;
      if (w2 < 1e-5f) w2 = 0.0f;
      if (w3 < 1e-5f) w3 = 0.0f;
      dc = isinf(d) ? 0.0f : d;
      if (idx < 0 || idx >= N) idx = 0;   // its w==0; safe address
    }
    wl[l][k][0] = w0; wl[l][k][1] = w1; wl[l][k][2] = w2; wl[l][k][3] = w3;
    dl[l][k] = dc; nl[l][k] = idx;
  }
  __syncthreads();

  int n = n0 + ln;
  if (n >= N) return;

  int   off[K1V];
  float dag0 = 0, dag1 = 0, dag2 = 0, dag3 = 0;
#pragma unroll
  for (int k = 0; k < K1V; ++k) {
    off[k] = nl[ln][k] * COUT + c;
    float4 wv = *(const float4*)wl[ln][k];
    float dc = dl[ln][k];
    dag0 = fmaf(wv.x, dc, dag0);
    dag1 = fmaf(wv.y, dc, dag1);
    dag2 = fmaf(wv.z, dc, dag2);
    dag3 = fmaf(wv.w, dc, dag3);
  }

  size_t slice = (size_t)N * COUT;
  for (int bt0 = 0; bt0 < BT; bt0 += BTILE) {
    float acc[BTILE][HV];
#pragma unroll
    for (int t = 0; t < BTILE; ++t) {
      acc[t][0] = dag0; acc[t][1] = dag1; acc[t][2] = dag2; acc[t][3] = dag3;
    }
    const float* base = xp + (size_t)bt0 * slice;
#pragma unroll
    for (int k = 0; k < K1V; ++k) {
      float4 wv = *(const float4*)wl[ln][k];
      float v[BTILE];
#pragma unroll
      for (int t = 0; t < BTILE; ++t) v[t] = base[(size_t)t * slice + off[k]];
#pragma unroll
      for (int t = 0; t < BTILE; ++t) {
        acc[t][0] = fmaf(wv.x, v[t], acc[t][0]);
        acc[t][1] = fmaf(wv.y, v[t], acc[t][1]);
        acc[t][2] = fmaf(wv.z, v[t], acc[t][2]);
        acc[t][3] = fmaf(wv.w, v[t], acc[t][3]);
      }
    }
#pragma unroll
    for (int t = 0; t < BTILE; ++t) {
#pragma unroll
      for (int h = 0; h < HV; ++h) {
        float* p = out + (((size_t)(bt0 + t) * N + n) * HV + h) * COUT + c;
        __builtin_nontemporal_store(acc[t][h], p);
      }
    }
  }
}

extern "C" void kernel_launch(void* const* d_in, const int* in_sizes, int n_in,
                              void* d_out, int out_size, void* d_ws, size_t ws_size,
                              hipStream_t stream) {
  const float* x    = (const float*)d_in[0];
  const float* W    = (const float*)d_in[1];
  const float* b    = (const float*)d_in[2];
  const float* dist = (const float*)d_in[3];
  const int*   nn   = (const int*)d_in[4];
  float* out = (float*)d_out;
  float* xp  = (float*)d_ws;   // (BT, N, 32) fp32 = 30.72 MB

  int  N  = in_sizes[4] / K1V;                 // 10000
  long M  = (long)in_sizes[0] / CIN;           // BT * N = 240000
  int  BT = (int)(M / N);                      // 24

  proj_kernel<<<(int)((M + 255) / 256), 256, 0, stream>>>(x, W, b, xp, M);

  int nblocks = (N + 7) / 8;                   // 1250
  gcn_kernel<<<nblocks, 256, 0, stream>>>(xp, dist, nn, out, BT, N);
}

// Round 5
// 86.941 us; speedup vs baseline: 4.8448x; 1.4498x over previous
//
#include <hip/hip_runtime.h>
#include <hip/hip_bf16.h>
#include <math.h>

#define CIN   64
#define COUT  32
#define K1V   17
#define HV    4
#define RPB   64          // rows per proj block
#define XPAD  68          // LDS row stride (floats): 272B, 16B-aligned, 4-way conflict (~free)

// Kernel A: xp[r,o] = sum_i x[r,i]*W[o,i] + b[o]
// Stage 64 rows in LDS (coalesced). Wave w owns output channels w*8..w*8+7
// (wave-uniform via readfirstlane -> W/b become s_loads on the scalar pipe).
// lane = row -> x fragments via ds_read_b128. 512 FMA vs 16 b128 per wave.
__global__ __launch_bounds__(256) void proj_kernel(
    const float* __restrict__ x, const float* __restrict__ W,
    const float* __restrict__ b, float* __restrict__ xp, long nrows) {
  __shared__ float Xl[RPB * XPAD];   // 17408 B
  int tid = threadIdx.x;
  long r0 = (long)blockIdx.x * RPB;

  // stage: 64 rows * 64 floats = 1024 float4, 256 threads x 4
  const float4* xg = (const float4*)(x + r0 * CIN);
#pragma unroll
  for (int s = 0; s < 4; ++s) {
    int fi  = tid + s * 256;          // float4 index in tile
    int row = fi >> 4;
    int col = (fi & 15) << 2;
    *(float4*)&Xl[row * XPAD + col] = xg[fi];
  }
  __syncthreads();

  int wv   = __builtin_amdgcn_readfirstlane(tid >> 6);  // wave id 0..3, SGPR
  int lane = tid & 63;                                  // row within tile
  long r = r0 + lane;
  if (r >= nrows) return;

  const float* Wb = W + wv * 8 * CIN;   // uniform base
  float acc[8];
#pragma unroll
  for (int oo = 0; oo < 8; ++oo) acc[oo] = b[wv * 8 + oo];

#pragma unroll
  for (int j = 0; j < CIN / 4; ++j) {
    float4 xv = *(const float4*)&Xl[lane * XPAD + j * 4];
#pragma unroll
    for (int oo = 0; oo < 8; ++oo) {
      float4 w4 = *(const float4*)(Wb + oo * CIN + j * 4);  // s_load_dwordx4
      acc[oo] = fmaf(xv.x, w4.x,
                fmaf(xv.y, w4.y,
                fmaf(xv.z, w4.z,
                fmaf(xv.w, w4.w, acc[oo]))));
    }
  }

  // xp[r][wv*8 .. wv*8+7]; the 4 waves of the block jointly fill each 128B row
  float* op = xp + r * COUT + wv * 8;
  *(float4*)op       = make_float4(acc[0], acc[1], acc[2], acc[3]);
  *(float4*)(op + 4) = make_float4(acc[4], acc[5], acc[6], acc[7]);
}

// Kernel C: grid (node_groups, BT). Block = 8 nodes x 32 ch for ONE bt slice.
// blockIdx.x fastest -> co-resident blocks share one 1.28MB slice (L2-hot).
// Builder threads make w/d/idx table; 32 threads fold dist_agg; main loop is
// 17 x {idx, w4, gather, 4 FMA}; nontemporal stores for out.
__global__ __launch_bounds__(256) void gcn_kernel(
    const float* __restrict__ xp,    // (BT, N, 32)
    const float* __restrict__ dist,  // (N, K1)
    const int*   __restrict__ nn,    // (N, K1)
    float* __restrict__ out,         // (BT, N, H, 32)
    int N) {
  __shared__ float wl[8][K1V][HV];
  __shared__ float dl[8][K1V];
  __shared__ int   nl[8][K1V];
  __shared__ float dagl[8][HV];

  int tid = threadIdx.x;
  int bt  = blockIdx.y;
  int n0  = blockIdx.x * 8;

  if (tid < 8 * K1V) {        // 136 builder threads
    int l = tid / K1V, k = tid % K1V;
    int n_ = n0 + l;
    float w0 = 0, w1 = 0, w2 = 0, w3 = 0, dc = 0;
    int idx = 0;
    if (n_ < N) {
      float d = dist[(long)n_ * K1V + k];
      idx = nn[(long)n_ * K1V + k];
      float d2 = d * d;
      w0 = __expf(-d2 * 0.25f);
      w1 = __expf(-d2 * 0.50f);
      w2 = __expf(-d2 * 0.75f);
      w3 = __expf(-d2);
      if (idx == -1) { w0 = w1 = w2 = w3 = 0.0f; }
      if (w0 < 1e-5f) w0 = 0.0f;
      if (w1 < 1e-5f) w1 = 0.0f;
      if (w2 < 1e-5f) w2 = 0.0f;
      if (w3 < 1e-5f) w3 = 0.0f;
      dc = isinf(d) ? 0.0f : d;
      if (idx < 0 || idx >= N) idx = 0;   // its w==0; safe address
    }
    wl[l][k][0] = w0; wl[l][k][1] = w1; wl[l][k][2] = w2; wl[l][k][3] = w3;
    dl[l][k] = dc; nl[l][k] = idx;
  }
  __syncthreads();

  if (tid < 8 * HV) {         // fold dist_agg once per (node, head)
    int l = tid >> 2, h = tid & 3;
    float s = 0.0f;
#pragma unroll
    for (int k = 0; k < K1V; ++k) s = fmaf(wl[l][k][h], dl[l][k], s);
    dagl[l][h] = s;
  }
  __syncthreads();

  int ln = tid >> 5;          // local node
  int c  = tid & 31;          // channel
  int n  = n0 + ln;
  if (n >= N) return;

  const float* base = xp + (size_t)bt * N * COUT + c;
  float a0 = dagl[ln][0], a1 = dagl[ln][1], a2 = dagl[ln][2], a3 = dagl[ln][3];

#pragma unroll
  for (int k = 0; k < K1V; ++k) {
    int   idx = nl[ln][k];
    float v   = base[(size_t)idx * COUT];
    float4 w4 = *(const float4*)wl[ln][k];
    a0 = fmaf(w4.x, v, a0);
    a1 = fmaf(w4.y, v, a1);
    a2 = fmaf(w4.z, v, a2);
    a3 = fmaf(w4.w, v, a3);
  }

  float* ob = out + (((size_t)bt * N + n) * HV) * COUT + c;
  __builtin_nontemporal_store(a0, ob);
  __builtin_nontemporal_store(a1, ob + COUT);
  __builtin_nontemporal_store(a2, ob + 2 * COUT);
  __builtin_nontemporal_store(a3, ob + 3 * COUT);
}

extern "C" void kernel_launch(void* const* d_in, const int* in_sizes, int n_in,
                              void* d_out, int out_size, void* d_ws, size_t ws_size,
                              hipStream_t stream) {
  const float* x    = (const float*)d_in[0];
  const float* W    = (const float*)d_in[1];
  const float* b    = (const float*)d_in[2];
  const float* dist = (const float*)d_in[3];
  const int*   nn   = (const int*)d_in[4];
  float* out = (float*)d_out;
  float* xp  = (float*)d_ws;   // (BT, N, 32) fp32 = 30.72 MB

  int  N  = in_sizes[4] / K1V;                 // 10000
  long M  = (long)in_sizes[0] / CIN;           // BT * N = 240000
  int  BT = (int)(M / N);                      // 24

  proj_kernel<<<(int)((M + RPB - 1) / RPB), 256, 0, stream>>>(x, W, b, xp, M);

  dim3 grid((N + 7) / 8, BT);                  // 1250 x 24 = 30000 blocks
  gcn_kernel<<<grid, 256, 0, stream>>>(xp, dist, nn, out, N);
}